// Round 15
// baseline (1594.400 us; speedup 1.0000x reference)
//
#include <hip/hip_runtime.h>
#include <hip/hip_bf16.h>

#define N_NODES 50000
#define N_EDGES 1600000
#define N_GRAPHS 64

typedef _Float16 f16;
typedef _Float16 f16x8 __attribute__((ext_vector_type(8)));
typedef _Float16 f16x4 __attribute__((ext_vector_type(4)));
typedef _Float16 f16x2 __attribute__((ext_vector_type(2)));
typedef float f32x4 __attribute__((ext_vector_type(4)));

// async global->LDS (16B per lane; LDS dest = wave-uniform base + lane*16)
typedef __attribute__((address_space(3))) void lds_void_t;
typedef const __attribute__((address_space(1))) void gbl_void_t;
__device__ __forceinline__ void gload_lds16(const void* g, void* l) {
    __builtin_amdgcn_global_load_lds((gbl_void_t*)g, (lds_void_t*)l, 16, 0, 0);
}

// ---------------------------------------------------------------------------
// Graph-structure construction
// ---------------------------------------------------------------------------
__global__ void init_deg(int* deg) {
    int i = blockIdx.x * blockDim.x + threadIdx.x;
    if (i < N_NODES) deg[i] = 1;  // self-loop
}

__global__ void deg_count(const int* __restrict__ dst, int* __restrict__ deg) {
    int e = blockIdx.x * blockDim.x + threadIdx.x;
    if (e < N_EDGES) atomicAdd(&deg[dst[e]], 1);
}

__global__ void make_dinv(const int* __restrict__ deg, float* __restrict__ dinv) {
    int i = blockIdx.x * blockDim.x + threadIdx.x;
    if (i < N_NODES) dinv[i] = rsqrtf((float)deg[i]);
}

// single-block scan over edge-only degrees -> rowstart[N+1], pos[N]
__global__ void scan_deg(const int* __restrict__ deg, int* __restrict__ rowstart,
                         int* __restrict__ pos) {
    __shared__ int wsum[16];
    __shared__ int carry_s;
    const int t = threadIdx.x;
    const int lane = t & 63;
    const int w = t >> 6;
    if (t == 0) carry_s = 0;
    __syncthreads();
    for (int base = 0; base < N_NODES; base += 1024) {
        int i = base + t;
        int v = (i < N_NODES) ? (deg[i] - 1) : 0;  // exclude self loop
        int s = v;
#pragma unroll
        for (int off = 1; off < 64; off <<= 1) {
            int n = __shfl_up(s, off, 64);
            if (lane >= off) s += n;
        }
        if (lane == 63) wsum[w] = s;
        __syncthreads();
        if (w == 0) {
            int ws = (lane < 16) ? wsum[lane] : 0;
#pragma unroll
            for (int off = 1; off < 16; off <<= 1) {
                int n = __shfl_up(ws, off, 64);
                if (lane >= off) ws += n;
            }
            if (lane < 16) wsum[lane] = ws;
        }
        __syncthreads();
        int waveoff = (w == 0) ? 0 : wsum[w - 1];
        int carry = carry_s;
        int excl = carry + waveoff + s - v;
        if (i < N_NODES) {
            rowstart[i] = excl;
            pos[i] = excl;
        }
        __syncthreads();
        if (t == 0) carry_s = carry + wsum[15];
        __syncthreads();
    }
    if (t == 0) rowstart[N_NODES] = carry_s;
}

// packed CSR entry: .x = src node, .y = norm (float bits)
__global__ void csr_fill(const int* __restrict__ src, const int* __restrict__ dst,
                         const float* __restrict__ dinv, int* __restrict__ pos,
                         int2* __restrict__ csr) {
    int e = blockIdx.x * blockDim.x + threadIdx.x;
    if (e >= N_EDGES) return;
    int s = src[e], d = dst[e];
    int slot = atomicAdd(&pos[d], 1);
    csr[slot] = make_int2(s, __float_as_int(dinv[s] * dinv[d]));
}

// ---------------------------------------------------------------------------
// Weight cast+transpose: Wt[n][k] = (f16) W[k][n]
// ---------------------------------------------------------------------------
__global__ void cast_w(const float* __restrict__ W, f16* __restrict__ Wt, int K, int N) {
    int i = blockIdx.x * blockDim.x + threadIdx.x;
    if (i >= K * N) return;
    int k = i % K, n = i / K;
    Wt[i] = (f16)W[(size_t)k * N + n];
}

// ---------------------------------------------------------------------------
// MFMA GEMM layer 0, LDS-staged (R11 barrier version — empirically best):
// block = 4 waves, tile 128 rows x 128 cols, split-K=2.  A staged via async
// global_load_lds (width 16), XOR chunk-swizzle (source pre-swizzled, read
// applies same XOR; LDS dest linear).
// ---------------------------------------------------------------------------
__launch_bounds__(256)
__global__ void gemm_x_lds(const float* __restrict__ A, const f16* __restrict__ Bt,
                           float* __restrict__ C0, float* __restrict__ C1, int M) {
    const int K = 1280;
    __shared__ float Asm[128 * 32];  // 16 KB
    const int t = threadIdx.x;
    const int w = t >> 6, lane = t & 63;
    const int tile = blockIdx.x >> 1, s = blockIdx.x & 1;
    const int m0 = tile * 128;
    const int kbeg = s * 640;
    float* __restrict__ C = s ? C1 : C0;
    const int r = lane & 15, q = lane >> 4;

    // staging: call i covers rows w*32+i*8 .. +8; lane l -> row +(l>>3), slot l&7
    const int rl_base = w * 32 + (lane >> 3);
    const int gchunk = (lane & 7) ^ ((lane >> 3) & 7);  // pre-swizzled source chunk

    // compute-side LDS addresses (swizzled read)
    const int row_l0 = w * 32 + r;
    const int row_l1 = w * 32 + 16 + r;
    const int sw = r & 7;
    const float* lr0a = Asm + row_l0 * 32 + (((2 * q) ^ sw) << 2);
    const float* lr0b = Asm + row_l0 * 32 + (((2 * q + 1) ^ sw) << 2);
    const float* lr1a = Asm + row_l1 * 32 + (((2 * q) ^ sw) << 2);
    const float* lr1b = Asm + row_l1 * 32 + (((2 * q + 1) ^ sw) << 2);

    const f16* bp = Bt + (size_t)r * K + kbeg + q * 8;

    f32x4 acc[2][8];
#pragma unroll
    for (int i = 0; i < 2; ++i)
#pragma unroll
        for (int j = 0; j < 8; ++j) acc[i][j] = (f32x4){0.f, 0.f, 0.f, 0.f};

    for (int kt = 0; kt < 20; ++kt) {
        const int kk = kbeg + kt * 32;
        // ---- async stage A tile (4 calls/wave, 16 KB/block) ----
#pragma unroll
        for (int i = 0; i < 4; ++i) {
            int row_g = m0 + rl_base + i * 8;
            row_g = row_g < M ? row_g : M - 1;
            const float* src = A + (size_t)row_g * K + kk + gchunk * 4;
            float* dst = Asm + (w * 32 + i * 8) * 32;  // wave-uniform base
            gload_lds16(src, dst);
        }
        __syncthreads();  // drains vmcnt before barrier
        // ---- fragments from LDS ----
        float4 u0 = *(const float4*)lr0a;
        float4 v0 = *(const float4*)lr0b;
        float4 u1 = *(const float4*)lr1a;
        float4 v1 = *(const float4*)lr1b;
        f16x8 af0 = {(f16)u0.x, (f16)u0.y, (f16)u0.z, (f16)u0.w,
                     (f16)v0.x, (f16)v0.y, (f16)v0.z, (f16)v0.w};
        f16x8 af1 = {(f16)u1.x, (f16)u1.y, (f16)u1.z, (f16)u1.w,
                     (f16)v1.x, (f16)v1.y, (f16)v1.z, (f16)v1.w};
#pragma unroll
        for (int ni = 0; ni < 8; ++ni) {
            f16x8 bf = *(const f16x8*)(bp + (size_t)ni * 16 * K + kt * 32);
            acc[0][ni] = __builtin_amdgcn_mfma_f32_16x16x32_f16(af0, bf, acc[0][ni], 0, 0, 0);
            acc[1][ni] = __builtin_amdgcn_mfma_f32_16x16x32_f16(af1, bf, acc[1][ni], 0, 0, 0);
        }
        __syncthreads();  // protect LDS before next stage
    }
#pragma unroll
    for (int mi = 0; mi < 2; ++mi)
#pragma unroll
        for (int j = 0; j < 4; ++j) {
            int row = m0 + w * 32 + mi * 16 + q * 4 + j;
            if (row < M) {
                float* cp = C + (size_t)row * 128 + r;
#pragma unroll
                for (int ni = 0; ni < 8; ++ni) cp[ni * 16] = acc[mi][ni][j];
            }
        }
}

// sum split-K partials, cast to f16 (vectorized x4)
__global__ void reduce_cast(const float* __restrict__ c0, const float* __restrict__ c1,
                            f16* __restrict__ o, int n4) {
    int i = blockIdx.x * blockDim.x + threadIdx.x;
    if (i >= n4) return;
    float4 a = ((const float4*)c0)[i];
    float4 b = ((const float4*)c1)[i];
    f16x4 r = {(f16)(a.x + b.x), (f16)(a.y + b.y), (f16)(a.z + b.z), (f16)(a.w + b.w)};
    ((f16x4*)o)[i] = r;
}

// ---------------------------------------------------------------------------
// MFMA GEMM layers 1/2, fused BN+ReLU on A, 32 rows/wave, 2-stage pipeline.
// ---------------------------------------------------------------------------
template <int K>
__launch_bounds__(256)
__global__ void gemm_h_bn_pipe(const f16* __restrict__ A16, const float* __restrict__ ss,
                               const f16* __restrict__ Bt, f16* __restrict__ C16, int N) {
    constexpr int NT = K / 32;
    const int gw = (int)((blockIdx.x * blockDim.x + threadIdx.x) >> 6);
    const int lane = threadIdx.x & 63;
    const int m0 = gw * 32;
    if (m0 >= N_NODES) return;
    const int col0 = blockIdx.y * 128;
    const int r = lane & 15, q = lane >> 4;
    int row0 = m0 + r;       row0 = row0 < N_NODES ? row0 : N_NODES - 1;
    int row1 = m0 + 16 + r;  row1 = row1 < N_NODES ? row1 : N_NODES - 1;
    const f16* a0 = A16 + (size_t)row0 * K + q * 8;
    const f16* a1 = A16 + (size_t)row1 * K + q * 8;
    const f16* bp = Bt + (size_t)(col0 + r) * K + q * 8;
    const float* scp = ss + q * 8;
    const float* shp = ss + K + q * 8;

    f32x4 acc[2][8];
#pragma unroll
    for (int i = 0; i < 2; ++i)
#pragma unroll
        for (int j = 0; j < 8; ++j) acc[i][j] = (f32x4){0.f, 0.f, 0.f, 0.f};

    f16x8 ab[2][2];
    f16x8 bb[2][8];
    float4 sb[2][4];  // scale lo/hi, shift lo/hi
    ab[0][0] = *(const f16x8*)(a0);
    ab[0][1] = *(const f16x8*)(a1);
    sb[0][0] = *(const float4*)(scp);
    sb[0][1] = *(const float4*)(scp + 4);
    sb[0][2] = *(const float4*)(shp);
    sb[0][3] = *(const float4*)(shp + 4);
#pragma unroll
    for (int ni = 0; ni < 8; ++ni) bb[0][ni] = *(const f16x8*)(bp + (size_t)ni * 16 * K);

#pragma unroll
    for (int kt = 0; kt < NT; ++kt) {
        const int cur = kt & 1, nxt = cur ^ 1;
        if (kt < NT - 1) {
            const int ko = (kt + 1) * 32;
            ab[nxt][0] = *(const f16x8*)(a0 + ko);
            ab[nxt][1] = *(const f16x8*)(a1 + ko);
            sb[nxt][0] = *(const float4*)(scp + ko);
            sb[nxt][1] = *(const float4*)(scp + ko + 4);
            sb[nxt][2] = *(const float4*)(shp + ko);
            sb[nxt][3] = *(const float4*)(shp + ko + 4);
#pragma unroll
            for (int ni = 0; ni < 8; ++ni)
                bb[nxt][ni] = *(const f16x8*)(bp + (size_t)ni * 16 * K + ko);
        }
        float sc[8] = {sb[cur][0].x, sb[cur][0].y, sb[cur][0].z, sb[cur][0].w,
                       sb[cur][1].x, sb[cur][1].y, sb[cur][1].z, sb[cur][1].w};
        float sh[8] = {sb[cur][2].x, sb[cur][2].y, sb[cur][2].z, sb[cur][2].w,
                       sb[cur][3].x, sb[cur][3].y, sb[cur][3].z, sb[cur][3].w};
        f16x8 af0, af1;
#pragma unroll
        for (int j = 0; j < 8; ++j) {
            float v0 = (float)ab[cur][0][j] * sc[j] + sh[j];
            float v1 = (float)ab[cur][1][j] * sc[j] + sh[j];
            af0[j] = (f16)(v0 > 0.f ? v0 : 0.f);
            af1[j] = (f16)(v1 > 0.f ? v1 : 0.f);
        }
#pragma unroll
        for (int ni = 0; ni < 8; ++ni) {
            acc[0][ni] = __builtin_amdgcn_mfma_f32_16x16x32_f16(af0, bb[cur][ni], acc[0][ni], 0, 0, 0);
            acc[1][ni] = __builtin_amdgcn_mfma_f32_16x16x32_f16(af1, bb[cur][ni], acc[1][ni], 0, 0, 0);
        }
    }
#pragma unroll
    for (int mi = 0; mi < 2; ++mi)
#pragma unroll
        for (int j = 0; j < 4; ++j) {
            int row = m0 + mi * 16 + q * 4 + j;
            if (row < N_NODES) {
                f16* cp = C16 + (size_t)row * N + col0 + r;
#pragma unroll
                for (int ni = 0; ni < 8; ++ni) cp[ni * 16] = (f16)acc[mi][ni][j];
            }
        }
}

// ---------------------------------------------------------------------------
// Edge aggregation, FEATURE-SLICED: one pass handles 32 features (64 B/row),
// so the per-pass gather working set = 50000*64B = 3.2 MB < 4 MB per-XCD L2.
// One wave per node, lanes 0..31 active (1 f16 feature each); 8-deep MLP.
// Passes launched as separate kernels (stream-serialized) to keep the slice
// L2-resident.  Per-feature summation order identical to monolithic version.
// ---------------------------------------------------------------------------
template <int D>
__launch_bounds__(256)
__global__ void aggregate_slice(const f16* __restrict__ h, const int* __restrict__ rowstart,
                                const int2* __restrict__ csr, const float* __restrict__ dinv,
                                const float* __restrict__ bias, f16* __restrict__ out,
                                int p32) {
    int w = (int)((blockIdx.x * blockDim.x + threadIdx.x) >> 6);
    int lane = threadIdx.x & 63;
    if (w >= N_NODES || lane >= 32) return;
    const f16* hs = h + p32 + lane;  // column-sliced view
    float di = dinv[w];
    float acc = (float)hs[(size_t)w * D] * (di * di);
    int e0 = rowstart[w], e1 = rowstart[w + 1];
    int j = e0;
    for (; j + 8 <= e1; j += 8) {
        int2 c[8];
        float rv[8];
#pragma unroll
        for (int u = 0; u < 8; ++u) c[u] = csr[j + u];
#pragma unroll
        for (int u = 0; u < 8; ++u) rv[u] = (float)hs[(size_t)c[u].x * D];
#pragma unroll
        for (int u = 0; u < 8; ++u) acc += rv[u] * __int_as_float(c[u].y);
    }
    for (; j < e1; ++j) {
        int2 c = csr[j];
        acc += (float)hs[(size_t)c.x * D] * __int_as_float(c.y);
    }
    out[(size_t)w * D + p32 + lane] = (f16)(acc + bias[p32 + lane]);
}

// ---------------------------------------------------------------------------
// BatchNorm stats (training, biased var) over pre-BN activations
// ---------------------------------------------------------------------------
template <int D>
__global__ void bn_stats(const f16* __restrict__ h, float* __restrict__ stat) {
    int f = threadIdx.x;  // D threads
    int r0 = blockIdx.x * 128;
    int r1 = min(r0 + 128, N_NODES);
    float s = 0.f, s2 = 0.f;
    for (int r = r0; r < r1; ++r) {
        float v = (float)h[(size_t)r * D + f];
        s += v;
        s2 += v * v;
    }
    atomicAdd(&stat[f], s);
    atomicAdd(&stat[D + f], s2);
}

template <int D>
__global__ void bn_finalize(const float* __restrict__ stat, const float* __restrict__ gamma,
                            const float* __restrict__ beta, float* __restrict__ ss) {
    int f = threadIdx.x;
    float m = stat[f] * (1.0f / N_NODES);
    float var = stat[D + f] * (1.0f / N_NODES) - m * m;
    float sc = gamma[f] * rsqrtf(var + 1e-5f);
    ss[f] = sc;
    ss[D + f] = beta[f] - m * sc;
}

// ---------------------------------------------------------------------------
// Pool (batch sorted) with fused BN+ReLU, + FC head
// ---------------------------------------------------------------------------
__global__ void count_batch_bs(const int* __restrict__ batch, int* __restrict__ cnt) {
    int g = threadIdx.x;  // one block, 64 threads
    if (g >= N_GRAPHS) return;
    int lo = 0, hi = N_NODES;
    while (lo < hi) { int mid = (lo + hi) >> 1; if (batch[mid] < g) lo = mid + 1; else hi = mid; }
    int b0 = lo;
    lo = 0; hi = N_NODES;
    while (lo < hi) { int mid = (lo + hi) >> 1; if (batch[mid] < g + 1) lo = mid + 1; else hi = mid; }
    cnt[g] = lo - b0;
}

__global__ void pool_seg_bn(const f16* __restrict__ h, const float* __restrict__ ss,
                            const int* __restrict__ batch, float* __restrict__ psum) {
    int f = threadIdx.x;  // 256
    float sc = ss[f], sh = ss[256 + f];
    int r0 = blockIdx.x * 64;
    int r1 = min(r0 + 64, N_NODES);
    float acc = 0.f;
    int cur = batch[r0];
    for (int r = r0; r < r1; ++r) {
        int b = batch[r];
        if (b != cur) {
            atomicAdd(&psum[cur * 256 + f], acc);
            acc = 0.f;
            cur = b;
        }
        float v = sc * (float)h[(size_t)r * 256 + f] + sh;
        acc += v > 0.f ? v : 0.f;
    }
    atomicAdd(&psum[cur * 256 + f], acc);
}

__global__ void pool_div(const float* __restrict__ psum, const int* __restrict__ cnt,
                         float* __restrict__ g) {
    int i = blockIdx.x * 256 + threadIdx.x;  // 64*256
    int b = i >> 8;
    float c = (float)max(cnt[b], 1);
    g[i] = psum[i] / c;
}

// ---- FC head: split-K with atomic accumulation (high TLP) ----
__global__ void fc_init(const float* __restrict__ b, float* __restrict__ Y, int rows, int N) {
    int i = blockIdx.x * blockDim.x + threadIdx.x;
    if (i < rows * N) Y[i] = b[i % N];
}

__global__ void fc_splitk(const float* __restrict__ X, const float* __restrict__ W,
                          float* __restrict__ Y, int K, int N, int KC) {
    int col = blockIdx.x * blockDim.x + threadIdx.x;
    int row = blockIdx.y;
    int k0 = blockIdx.z * KC;
    float acc = 0.f;
    const float* x = X + (size_t)row * K + k0;
    const float* w = W + (size_t)k0 * N + col;
#pragma unroll 8
    for (int k = 0; k < KC; ++k) acc += x[k] * w[(size_t)k * N];
    atomicAdd(&Y[(size_t)row * N + col], acc);
}

__global__ void relu_inplace(float* __restrict__ Y, int n) {
    int i = blockIdx.x * blockDim.x + threadIdx.x;
    if (i < n) Y[i] = Y[i] > 0.f ? Y[i] : 0.f;
}

// ---------------------------------------------------------------------------
extern "C" void kernel_launch(void* const* d_in, const int* in_sizes, int n_in,
                              void* d_out, int out_size, void* d_ws, size_t ws_size,
                              hipStream_t stream) {
    const float* x     = (const float*)d_in[0];
    const int*   ei    = (const int*)d_in[1];   // [2][E]: row0=src, row1=dst
    const int*   batch = (const int*)d_in[2];
    const float* Wg0 = (const float*)d_in[3],  *bg0 = (const float*)d_in[4];
    const float* gamma0 = (const float*)d_in[5], *beta0 = (const float*)d_in[6];
    const float* Wg1 = (const float*)d_in[7],  *bg1 = (const float*)d_in[8];
    const float* gamma1 = (const float*)d_in[9], *beta1 = (const float*)d_in[10];
    const float* Wg2 = (const float*)d_in[11], *bg2 = (const float*)d_in[12];
    const float* gamma2 = (const float*)d_in[13], *beta2 = (const float*)d_in[14];
    const float* Wf0 = (const float*)d_in[15], *bf0 = (const float*)d_in[16];
    const float* Wf1 = (const float*)d_in[17], *bf1 = (const float*)d_in[18];
    float* out = (float*)d_out;

    // ---- workspace carve (~120 MB; split-K partials alias f16 intermediates) ----
    size_t off = 0;
    auto alloc = [&](size_t bytes) {
        void* p = (char*)d_ws + off;
        off += (bytes + 255) & ~(size_t)255;
        return p;
    };
    f16*   hA16     = (f16*)alloc((size_t)N_NODES * 256 * 2);       // GEMM out (gather src)
    float* cp32     = (float*)alloc((size_t)2 * N_NODES * 128 * 4); // split-K partials (layer 0)
    f16*   hBn16    = (f16*)cp32;                                    // agg out / pre-BN (aliases cp0)
    float* cp0      = cp32;
    float* cp1      = cp32 + (size_t)N_NODES * 128;
    int2*  csr      = (int2*)alloc((size_t)N_EDGES * 8);
    int*   deg      = (int*)alloc((size_t)N_NODES * 4);
    float* dinv     = (float*)alloc((size_t)N_NODES * 4);
    int*   rowstart = (int*)alloc((size_t)(N_NODES + 1) * 4);
    int*   pos      = (int*)alloc((size_t)N_NODES * 4);
    float* bnstat   = (float*)alloc(2 * 256 * 4);
    float* bnss     = (float*)alloc(2 * 256 * 4);
    float* psum     = (float*)alloc(64 * 256 * 4);
    int*   pcount   = (int*)alloc(64 * 4);
    float* gpool    = (float*)alloc(64 * 256 * 4);
    float* g1       = (float*)alloc(64 * 1024 * 4);
    f16*   W0t      = (f16*)alloc((size_t)1280 * 128 * 2);
    f16*   W1t      = (f16*)alloc((size_t)128 * 256 * 2);
    f16*   W2t      = (f16*)alloc((size_t)256 * 256 * 2);
    (void)ws_size;

    const int TPB = 256;
    const int nb_nodes = (N_NODES + TPB - 1) / TPB;
    const int nb_edges = (N_EDGES + TPB - 1) / TPB;

    // ---- graph structure + weight casts ----
    init_deg<<<nb_nodes, TPB, 0, stream>>>(deg);
    deg_count<<<nb_edges, TPB, 0, stream>>>(ei + N_EDGES, deg);
    make_dinv<<<nb_nodes, TPB, 0, stream>>>(deg, dinv);
    scan_deg<<<1, 1024, 0, stream>>>(deg, rowstart, pos);
    csr_fill<<<nb_edges, TPB, 0, stream>>>(ei, ei + N_EDGES, dinv, pos, csr);
    cast_w<<<(1280 * 128 + 255) / 256, 256, 0, stream>>>(Wg0, W0t, 1280, 128);
    cast_w<<<(128 * 256 + 255) / 256, 256, 0, stream>>>(Wg1, W1t, 128, 256);
    cast_w<<<(256 * 256 + 255) / 256, 256, 0, stream>>>(Wg2, W2t, 256, 256);

    const int tiles128 = (N_NODES + 127) / 128;                   // 391
    const int gemm0_blocks = tiles128 * 2;                        // 782 (tile, split)
    const int gemmh_blocks = (1563 * 64 + TPB - 1) / TPB;         // 391
    const int agg_blocks = (N_NODES + 3) / 4;                     // 12500 (4 waves/block)

    // ---- layer 0: 1280 -> 128 (LDS-staged barrier version, split-K=2) ----
    gemm_x_lds<<<gemm0_blocks, TPB, 0, stream>>>(x, W0t, cp0, cp1, N_NODES);
    reduce_cast<<<(N_NODES * 128 / 4 + 255) / 256, 256, 0, stream>>>(cp0, cp1, hA16, N_NODES * 128 / 4);
    for (int p = 0; p < 4; ++p)
        aggregate_slice<128><<<agg_blocks, TPB, 0, stream>>>(hA16, rowstart, csr, dinv, bg0, hBn16, p * 32);
    hipMemsetAsync(bnstat, 0, 2 * 128 * 4, stream);
    bn_stats<128><<<(N_NODES + 127) / 128, 128, 0, stream>>>(hBn16, bnstat);
    bn_finalize<128><<<1, 128, 0, stream>>>(bnstat, gamma0, beta0, bnss);

    // ---- layer 1: 128 -> 256 (BN+ReLU fused into pipelined A-load) ----
    gemm_h_bn_pipe<128><<<dim3(gemmh_blocks, 2), TPB, 0, stream>>>(hBn16, bnss, W1t, hA16, 256);
    for (int p = 0; p < 8; ++p)
        aggregate_slice<256><<<agg_blocks, TPB, 0, stream>>>(hA16, rowstart, csr, dinv, bg1, hBn16, p * 32);
    hipMemsetAsync(bnstat, 0, 2 * 256 * 4, stream);
    bn_stats<256><<<(N_NODES + 127) / 128, 256, 0, stream>>>(hBn16, bnstat);
    bn_finalize<256><<<1, 256, 0, stream>>>(bnstat, gamma1, beta1, bnss);

    // ---- layer 2: 256 -> 256 (BN+ReLU fused into pipelined A-load) ----
    gemm_h_bn_pipe<256><<<dim3(gemmh_blocks, 2), TPB, 0, stream>>>(hBn16, bnss, W2t, hA16, 256);
    for (int p = 0; p < 8; ++p)
        aggregate_slice<256><<<agg_blocks, TPB, 0, stream>>>(hA16, rowstart, csr, dinv, bg2, hBn16, p * 32);
    hipMemsetAsync(bnstat, 0, 2 * 256 * 4, stream);
    bn_stats<256><<<(N_NODES + 127) / 128, 256, 0, stream>>>(hBn16, bnstat);
    bn_finalize<256><<<1, 256, 0, stream>>>(bnstat, gamma2, beta2, bnss);

    // ---- global mean pool (BN+ReLU fused) ----
    hipMemsetAsync(psum, 0, 64 * 256 * 4, stream);
    count_batch_bs<<<1, 64, 0, stream>>>(batch, pcount);
    pool_seg_bn<<<(N_NODES + 63) / 64, 256, 0, stream>>>(hBn16, bnss, batch, psum);
    pool_div<<<64, 256, 0, stream>>>(psum, pcount, gpool);

    // ---- FC head (split-K, atomic accumulate) ----
    fc_init<<<(64 * 1024 + 255) / 256, 256, 0, stream>>>(bf0, g1, 64, 1024);
    fc_splitk<<<dim3(4, 64, 4), 256, 0, stream>>>(gpool, Wf0, g1, 256, 1024, 64);
    relu_inplace<<<(64 * 1024 + 255) / 256, 256, 0, stream>>>(g1, 64 * 1024);
    fc_init<<<(64 * 128 + 255) / 256, 256, 0, stream>>>(bf1, out, 64, 128);
    fc_splitk<<<dim3(1, 64, 16), 128, 0, stream>>>(g1, Wf1, out, 1024, 128, 64);
}

// Round 16
// 811.247 us; speedup vs baseline: 1.9654x; 1.9654x over previous
//
#include <hip/hip_runtime.h>
#include <hip/hip_bf16.h>

#define N_NODES 50000
#define N_EDGES 1600000
#define N_GRAPHS 64

typedef _Float16 f16;
typedef _Float16 f16x8 __attribute__((ext_vector_type(8)));
typedef _Float16 f16x4 __attribute__((ext_vector_type(4)));
typedef _Float16 f16x2 __attribute__((ext_vector_type(2)));
typedef float f32x4 __attribute__((ext_vector_type(4)));

template <int V> struct VecT;
template <> struct VecT<2> { using type = f16x2; };
template <> struct VecT<4> { using type = f16x4; };

// async global->LDS (16B per lane; LDS dest = wave-uniform base + lane*16)
typedef __attribute__((address_space(3))) void lds_void_t;
typedef const __attribute__((address_space(1))) void gbl_void_t;
__device__ __forceinline__ void gload_lds16(const void* g, void* l) {
    __builtin_amdgcn_global_load_lds((gbl_void_t*)g, (lds_void_t*)l, 16, 0, 0);
}

// ---------------------------------------------------------------------------
// Graph-structure construction
// ---------------------------------------------------------------------------
__global__ void init_deg(int* deg) {
    int i = blockIdx.x * blockDim.x + threadIdx.x;
    if (i < N_NODES) deg[i] = 1;  // self-loop
}

__global__ void deg_count(const int* __restrict__ dst, int* __restrict__ deg) {
    int e = blockIdx.x * blockDim.x + threadIdx.x;
    if (e < N_EDGES) atomicAdd(&deg[dst[e]], 1);
}

__global__ void make_dinv(const int* __restrict__ deg, float* __restrict__ dinv) {
    int i = blockIdx.x * blockDim.x + threadIdx.x;
    if (i < N_NODES) dinv[i] = rsqrtf((float)deg[i]);
}

// single-block scan over edge-only degrees -> rowstart[N+1], pos[N]
__global__ void scan_deg(const int* __restrict__ deg, int* __restrict__ rowstart,
                         int* __restrict__ pos) {
    __shared__ int wsum[16];
    __shared__ int carry_s;
    const int t = threadIdx.x;
    const int lane = t & 63;
    const int w = t >> 6;
    if (t == 0) carry_s = 0;
    __syncthreads();
    for (int base = 0; base < N_NODES; base += 1024) {
        int i = base + t;
        int v = (i < N_NODES) ? (deg[i] - 1) : 0;  // exclude self loop
        int s = v;
#pragma unroll
        for (int off = 1; off < 64; off <<= 1) {
            int n = __shfl_up(s, off, 64);
            if (lane >= off) s += n;
        }
        if (lane == 63) wsum[w] = s;
        __syncthreads();
        if (w == 0) {
            int ws = (lane < 16) ? wsum[lane] : 0;
#pragma unroll
            for (int off = 1; off < 16; off <<= 1) {
                int n = __shfl_up(ws, off, 64);
                if (lane >= off) ws += n;
            }
            if (lane < 16) wsum[lane] = ws;
        }
        __syncthreads();
        int waveoff = (w == 0) ? 0 : wsum[w - 1];
        int carry = carry_s;
        int excl = carry + waveoff + s - v;
        if (i < N_NODES) {
            rowstart[i] = excl;
            pos[i] = excl;
        }
        __syncthreads();
        if (t == 0) carry_s = carry + wsum[15];
        __syncthreads();
    }
    if (t == 0) rowstart[N_NODES] = carry_s;
}

// packed CSR entry: .x = src node, .y = norm (float bits)
__global__ void csr_fill(const int* __restrict__ src, const int* __restrict__ dst,
                         const float* __restrict__ dinv, int* __restrict__ pos,
                         int2* __restrict__ csr) {
    int e = blockIdx.x * blockDim.x + threadIdx.x;
    if (e >= N_EDGES) return;
    int s = src[e], d = dst[e];
    int slot = atomicAdd(&pos[d], 1);
    csr[slot] = make_int2(s, __float_as_int(dinv[s] * dinv[d]));
}

// ---------------------------------------------------------------------------
// Weight cast+transpose: Wt[n][k] = (f16) W[k][n]
// ---------------------------------------------------------------------------
__global__ void cast_w(const float* __restrict__ W, f16* __restrict__ Wt, int K, int N) {
    int i = blockIdx.x * blockDim.x + threadIdx.x;
    if (i >= K * N) return;
    int k = i % K, n = i / K;
    Wt[i] = (f16)W[(size_t)k * N + n];
}

// ---------------------------------------------------------------------------
// MFMA GEMM layer 0, LDS-staged (R11 barrier version — empirically best):
// block = 4 waves, tile 128 rows x 128 cols, split-K=2.
// ---------------------------------------------------------------------------
__launch_bounds__(256)
__global__ void gemm_x_lds(const float* __restrict__ A, const f16* __restrict__ Bt,
                           float* __restrict__ C0, float* __restrict__ C1, int M) {
    const int K = 1280;
    __shared__ float Asm[128 * 32];  // 16 KB
    const int t = threadIdx.x;
    const int w = t >> 6, lane = t & 63;
    const int tile = blockIdx.x >> 1, s = blockIdx.x & 1;
    const int m0 = tile * 128;
    const int kbeg = s * 640;
    float* __restrict__ C = s ? C1 : C0;
    const int r = lane & 15, q = lane >> 4;

    const int rl_base = w * 32 + (lane >> 3);
    const int gchunk = (lane & 7) ^ ((lane >> 3) & 7);  // pre-swizzled source chunk

    const int row_l0 = w * 32 + r;
    const int row_l1 = w * 32 + 16 + r;
    const int sw = r & 7;
    const float* lr0a = Asm + row_l0 * 32 + (((2 * q) ^ sw) << 2);
    const float* lr0b = Asm + row_l0 * 32 + (((2 * q + 1) ^ sw) << 2);
    const float* lr1a = Asm + row_l1 * 32 + (((2 * q) ^ sw) << 2);
    const float* lr1b = Asm + row_l1 * 32 + (((2 * q + 1) ^ sw) << 2);

    const f16* bp = Bt + (size_t)r * K + kbeg + q * 8;

    f32x4 acc[2][8];
#pragma unroll
    for (int i = 0; i < 2; ++i)
#pragma unroll
        for (int j = 0; j < 8; ++j) acc[i][j] = (f32x4){0.f, 0.f, 0.f, 0.f};

    for (int kt = 0; kt < 20; ++kt) {
        const int kk = kbeg + kt * 32;
#pragma unroll
        for (int i = 0; i < 4; ++i) {
            int row_g = m0 + rl_base + i * 8;
            row_g = row_g < M ? row_g : M - 1;
            const float* src = A + (size_t)row_g * K + kk + gchunk * 4;
            float* dst = Asm + (w * 32 + i * 8) * 32;  // wave-uniform base
            gload_lds16(src, dst);
        }
        __syncthreads();
        float4 u0 = *(const float4*)lr0a;
        float4 v0 = *(const float4*)lr0b;
        float4 u1 = *(const float4*)lr1a;
        float4 v1 = *(const float4*)lr1b;
        f16x8 af0 = {(f16)u0.x, (f16)u0.y, (f16)u0.z, (f16)u0.w,
                     (f16)v0.x, (f16)v0.y, (f16)v0.z, (f16)v0.w};
        f16x8 af1 = {(f16)u1.x, (f16)u1.y, (f16)u1.z, (f16)u1.w,
                     (f16)v1.x, (f16)v1.y, (f16)v1.z, (f16)v1.w};
#pragma unroll
        for (int ni = 0; ni < 8; ++ni) {
            f16x8 bf = *(const f16x8*)(bp + (size_t)ni * 16 * K + kt * 32);
            acc[0][ni] = __builtin_amdgcn_mfma_f32_16x16x32_f16(af0, bf, acc[0][ni], 0, 0, 0);
            acc[1][ni] = __builtin_amdgcn_mfma_f32_16x16x32_f16(af1, bf, acc[1][ni], 0, 0, 0);
        }
        __syncthreads();
    }
#pragma unroll
    for (int mi = 0; mi < 2; ++mi)
#pragma unroll
        for (int j = 0; j < 4; ++j) {
            int row = m0 + w * 32 + mi * 16 + q * 4 + j;
            if (row < M) {
                float* cp = C + (size_t)row * 128 + r;
#pragma unroll
                for (int ni = 0; ni < 8; ++ni) cp[ni * 16] = acc[mi][ni][j];
            }
        }
}

// sum split-K partials, cast to f16 (vectorized x4)
__global__ void reduce_cast(const float* __restrict__ c0, const float* __restrict__ c1,
                            f16* __restrict__ o, int n4) {
    int i = blockIdx.x * blockDim.x + threadIdx.x;
    if (i >= n4) return;
    float4 a = ((const float4*)c0)[i];
    float4 b = ((const float4*)c1)[i];
    f16x4 r = {(f16)(a.x + b.x), (f16)(a.y + b.y), (f16)(a.z + b.z), (f16)(a.w + b.w)};
    ((f16x4*)o)[i] = r;
}

// ---------------------------------------------------------------------------
// MFMA GEMM, fused BN+ReLU on A (layer 2), 32 rows/wave, 2-stage pipeline.
// ---------------------------------------------------------------------------
template <int K>
__launch_bounds__(256)
__global__ void gemm_h_bn_pipe(const f16* __restrict__ A16, const float* __restrict__ ss,
                               const f16* __restrict__ Bt, f16* __restrict__ C16, int N) {
    constexpr int NT = K / 32;
    const int gw = (int)((blockIdx.x * blockDim.x + threadIdx.x) >> 6);
    const int lane = threadIdx.x & 63;
    const int m0 = gw * 32;
    if (m0 >= N_NODES) return;
    const int col0 = blockIdx.y * 128;
    const int r = lane & 15, q = lane >> 4;
    int row0 = m0 + r;       row0 = row0 < N_NODES ? row0 : N_NODES - 1;
    int row1 = m0 + 16 + r;  row1 = row1 < N_NODES ? row1 : N_NODES - 1;
    const f16* a0 = A16 + (size_t)row0 * K + q * 8;
    const f16* a1 = A16 + (size_t)row1 * K + q * 8;
    const f16* bp = Bt + (size_t)(col0 + r) * K + q * 8;
    const float* scp = ss + q * 8;
    const float* shp = ss + K + q * 8;

    f32x4 acc[2][8];
#pragma unroll
    for (int i = 0; i < 2; ++i)
#pragma unroll
        for (int j = 0; j < 8; ++j) acc[i][j] = (f32x4){0.f, 0.f, 0.f, 0.f};

    f16x8 ab[2][2];
    f16x8 bb[2][8];
    float4 sb[2][4];
    ab[0][0] = *(const f16x8*)(a0);
    ab[0][1] = *(const f16x8*)(a1);
    sb[0][0] = *(const float4*)(scp);
    sb[0][1] = *(const float4*)(scp + 4);
    sb[0][2] = *(const float4*)(shp);
    sb[0][3] = *(const float4*)(shp + 4);
#pragma unroll
    for (int ni = 0; ni < 8; ++ni) bb[0][ni] = *(const f16x8*)(bp + (size_t)ni * 16 * K);

#pragma unroll
    for (int kt = 0; kt < NT; ++kt) {
        const int cur = kt & 1, nxt = cur ^ 1;
        if (kt < NT - 1) {
            const int ko = (kt + 1) * 32;
            ab[nxt][0] = *(const f16x8*)(a0 + ko);
            ab[nxt][1] = *(const f16x8*)(a1 + ko);
            sb[nxt][0] = *(const float4*)(scp + ko);
            sb[nxt][1] = *(const float4*)(scp + ko + 4);
            sb[nxt][2] = *(const float4*)(shp + ko);
            sb[nxt][3] = *(const float4*)(shp + ko + 4);
#pragma unroll
            for (int ni = 0; ni < 8; ++ni)
                bb[nxt][ni] = *(const f16x8*)(bp + (size_t)ni * 16 * K + ko);
        }
        float sc[8] = {sb[cur][0].x, sb[cur][0].y, sb[cur][0].z, sb[cur][0].w,
                       sb[cur][1].x, sb[cur][1].y, sb[cur][1].z, sb[cur][1].w};
        float sh[8] = {sb[cur][2].x, sb[cur][2].y, sb[cur][2].z, sb[cur][2].w,
                       sb[cur][3].x, sb[cur][3].y, sb[cur][3].z, sb[cur][3].w};
        f16x8 af0, af1;
#pragma unroll
        for (int j = 0; j < 8; ++j) {
            float v0 = (float)ab[cur][0][j] * sc[j] + sh[j];
            float v1 = (float)ab[cur][1][j] * sc[j] + sh[j];
            af0[j] = (f16)(v0 > 0.f ? v0 : 0.f);
            af1[j] = (f16)(v1 > 0.f ? v1 : 0.f);
        }
#pragma unroll
        for (int ni = 0; ni < 8; ++ni) {
            acc[0][ni] = __builtin_amdgcn_mfma_f32_16x16x32_f16(af0, bb[cur][ni], acc[0][ni], 0, 0, 0);
            acc[1][ni] = __builtin_amdgcn_mfma_f32_16x16x32_f16(af1, bb[cur][ni], acc[1][ni], 0, 0, 0);
        }
    }
#pragma unroll
    for (int mi = 0; mi < 2; ++mi)
#pragma unroll
        for (int j = 0; j < 4; ++j) {
            int row = m0 + mi * 16 + q * 4 + j;
            if (row < N_NODES) {
                f16* cp = C16 + (size_t)row * N + col0 + r;
#pragma unroll
                for (int ni = 0; ni < 8; ++ni) cp[ni * 16] = (f16)acc[mi][ni][j];
            }
        }
}

// ---------------------------------------------------------------------------
// MFMA GEMM, plain A + bias in epilogue (layer 1, aggregate-first order):
// C = A @ Bt^T + bias.  32 rows/wave, 2-stage register pipeline.
// ---------------------------------------------------------------------------
template <int K>
__launch_bounds__(256)
__global__ void gemm_h_bias_pipe(const f16* __restrict__ A16, const f16* __restrict__ Bt,
                                 const float* __restrict__ bias, f16* __restrict__ C16, int N) {
    constexpr int NT = K / 32;
    const int gw = (int)((blockIdx.x * blockDim.x + threadIdx.x) >> 6);
    const int lane = threadIdx.x & 63;
    const int m0 = gw * 32;
    if (m0 >= N_NODES) return;
    const int col0 = blockIdx.y * 128;
    const int r = lane & 15, q = lane >> 4;
    int row0 = m0 + r;       row0 = row0 < N_NODES ? row0 : N_NODES - 1;
    int row1 = m0 + 16 + r;  row1 = row1 < N_NODES ? row1 : N_NODES - 1;
    const f16* a0 = A16 + (size_t)row0 * K + q * 8;
    const f16* a1 = A16 + (size_t)row1 * K + q * 8;
    const f16* bp = Bt + (size_t)(col0 + r) * K + q * 8;

    f32x4 acc[2][8];
#pragma unroll
    for (int i = 0; i < 2; ++i)
#pragma unroll
        for (int j = 0; j < 8; ++j) acc[i][j] = (f32x4){0.f, 0.f, 0.f, 0.f};

    f16x8 ab[2][2];
    f16x8 bb[2][8];
    ab[0][0] = *(const f16x8*)(a0);
    ab[0][1] = *(const f16x8*)(a1);
#pragma unroll
    for (int ni = 0; ni < 8; ++ni) bb[0][ni] = *(const f16x8*)(bp + (size_t)ni * 16 * K);

#pragma unroll
    for (int kt = 0; kt < NT; ++kt) {
        const int cur = kt & 1, nxt = cur ^ 1;
        if (kt < NT - 1) {
            const int ko = (kt + 1) * 32;
            ab[nxt][0] = *(const f16x8*)(a0 + ko);
            ab[nxt][1] = *(const f16x8*)(a1 + ko);
#pragma unroll
            for (int ni = 0; ni < 8; ++ni)
                bb[nxt][ni] = *(const f16x8*)(bp + (size_t)ni * 16 * K + ko);
        }
#pragma unroll
        for (int ni = 0; ni < 8; ++ni) {
            acc[0][ni] = __builtin_amdgcn_mfma_f32_16x16x32_f16(ab[cur][0], bb[cur][ni], acc[0][ni], 0, 0, 0);
            acc[1][ni] = __builtin_amdgcn_mfma_f32_16x16x32_f16(ab[cur][1], bb[cur][ni], acc[1][ni], 0, 0, 0);
        }
    }
    float bv[8];
#pragma unroll
    for (int ni = 0; ni < 8; ++ni) bv[ni] = bias[col0 + ni * 16 + r];
#pragma unroll
    for (int mi = 0; mi < 2; ++mi)
#pragma unroll
        for (int j = 0; j < 4; ++j) {
            int row = m0 + mi * 16 + q * 4 + j;
            if (row < N_NODES) {
                f16* cp = C16 + (size_t)row * N + col0 + r;
#pragma unroll
                for (int ni = 0; ni < 8; ++ni) cp[ni * 16] = (f16)(acc[mi][ni][j] + bv[ni]);
            }
        }
}

// ---------------------------------------------------------------------------
// Edge aggregation (f16 gather, fp32 accumulate, f16 out): one wave per node.
// 8-deep unrolled gather loop.  BIAS toggles the +bias epilogue.
// ---------------------------------------------------------------------------
template <int D, bool BIAS>
__launch_bounds__(256)
__global__ void aggregate(const f16* __restrict__ h, const int* __restrict__ rowstart,
                          const int2* __restrict__ csr, const float* __restrict__ dinv,
                          const float* __restrict__ bias, f16* __restrict__ out) {
    constexpr int V = D / 64;  // f16 per lane (2 or 4)
    using vec = typename VecT<V>::type;
    int w = (int)((blockIdx.x * blockDim.x + threadIdx.x) >> 6);
    int lane = threadIdx.x & 63;
    if (w >= N_NODES) return;
    float acc[V];
    float di = dinv[w];
    vec self = *(const vec*)(h + (size_t)w * D + lane * V);
#pragma unroll
    for (int v = 0; v < V; ++v) acc[v] = (float)self[v] * (di * di);
    int e0 = rowstart[w], e1 = rowstart[w + 1];
    int j = e0;
    for (; j + 8 <= e1; j += 8) {
        int2 c[8];
        vec rr[8];
#pragma unroll
        for (int u = 0; u < 8; ++u) c[u] = csr[j + u];
#pragma unroll
        for (int u = 0; u < 8; ++u)
            rr[u] = *(const vec*)(h + (size_t)c[u].x * D + lane * V);
#pragma unroll
        for (int u = 0; u < 8; ++u) {
            float nm = __int_as_float(c[u].y);
#pragma unroll
            for (int v = 0; v < V; ++v) acc[v] += (float)rr[u][v] * nm;
        }
    }
    if (j + 4 <= e1) {
        int2 c0 = csr[j], c1 = csr[j + 1], c2 = csr[j + 2], c3 = csr[j + 3];
        vec r0 = *(const vec*)(h + (size_t)c0.x * D + lane * V);
        vec r1 = *(const vec*)(h + (size_t)c1.x * D + lane * V);
        vec r2 = *(const vec*)(h + (size_t)c2.x * D + lane * V);
        vec r3 = *(const vec*)(h + (size_t)c3.x * D + lane * V);
        float n0 = __int_as_float(c0.y), n1 = __int_as_float(c1.y);
        float n2 = __int_as_float(c2.y), n3 = __int_as_float(c3.y);
#pragma unroll
        for (int v = 0; v < V; ++v)
            acc[v] += (float)r0[v] * n0 + (float)r1[v] * n1 +
                      (float)r2[v] * n2 + (float)r3[v] * n3;
        j += 4;
    }
    for (; j < e1; ++j) {
        int2 c = csr[j];
        vec r = *(const vec*)(h + (size_t)c.x * D + lane * V);
        float nm = __int_as_float(c.y);
#pragma unroll
        for (int v = 0; v < V; ++v) acc[v] += (float)r[v] * nm;
    }
    vec o;
#pragma unroll
    for (int v = 0; v < V; ++v)
        o[v] = (f16)(BIAS ? (acc[v] + bias[lane * V + v]) : acc[v]);
    *(vec*)(out + (size_t)w * D + lane * V) = o;
}

// ---------------------------------------------------------------------------
// BatchNorm stats (training, biased var) over pre-BN activations
// ---------------------------------------------------------------------------
template <int D>
__global__ void bn_stats(const f16* __restrict__ h, float* __restrict__ stat) {
    int f = threadIdx.x;  // D threads
    int r0 = blockIdx.x * 128;
    int r1 = min(r0 + 128, N_NODES);
    float s = 0.f, s2 = 0.f;
    for (int r = r0; r < r1; ++r) {
        float v = (float)h[(size_t)r * D + f];
        s += v;
        s2 += v * v;
    }
    atomicAdd(&stat[f], s);
    atomicAdd(&stat[D + f], s2);
}

template <int D>
__global__ void bn_finalize(const float* __restrict__ stat, const float* __restrict__ gamma,
                            const float* __restrict__ beta, float* __restrict__ ss) {
    int f = threadIdx.x;
    float m = stat[f] * (1.0f / N_NODES);
    float var = stat[D + f] * (1.0f / N_NODES) - m * m;
    float sc = gamma[f] * rsqrtf(var + 1e-5f);
    ss[f] = sc;
    ss[D + f] = beta[f] - m * sc;
}

// BN+ReLU apply pass: hout = relu(sc*hin + sh), f16 in/out, vectorized x8
template <int D>
__global__ void bn_apply_relu(const f16* __restrict__ hin, const float* __restrict__ ss,
                              f16* __restrict__ hout) {
    int i = blockIdx.x * blockDim.x + threadIdx.x;  // 8 f16 per thread
    if (i >= N_NODES * D / 8) return;
    int f0 = (i * 8) & (D - 1);
    f16x8 v = ((const f16x8*)hin)[i];
    f16x8 r;
#pragma unroll
    for (int j = 0; j < 8; ++j) {
        float val = (float)v[j] * ss[f0 + j] + ss[D + f0 + j];
        r[j] = (f16)(val > 0.f ? val : 0.f);
    }
    ((f16x8*)hout)[i] = r;
}

// ---------------------------------------------------------------------------
// Pool (batch sorted) with fused BN+ReLU, + FC head
// ---------------------------------------------------------------------------
__global__ void count_batch_bs(const int* __restrict__ batch, int* __restrict__ cnt) {
    int g = threadIdx.x;  // one block, 64 threads
    if (g >= N_GRAPHS) return;
    int lo = 0, hi = N_NODES;
    while (lo < hi) { int mid = (lo + hi) >> 1; if (batch[mid] < g) lo = mid + 1; else hi = mid; }
    int b0 = lo;
    lo = 0; hi = N_NODES;
    while (lo < hi) { int mid = (lo + hi) >> 1; if (batch[mid] < g + 1) lo = mid + 1; else hi = mid; }
    cnt[g] = lo - b0;
}

__global__ void pool_seg_bn(const f16* __restrict__ h, const float* __restrict__ ss,
                            const int* __restrict__ batch, float* __restrict__ psum) {
    int f = threadIdx.x;  // 256
    float sc = ss[f], sh = ss[256 + f];
    int r0 = blockIdx.x * 64;
    int r1 = min(r0 + 64, N_NODES);
    float acc = 0.f;
    int cur = batch[r0];
    for (int r = r0; r < r1; ++r) {
        int b = batch[r];
        if (b != cur) {
            atomicAdd(&psum[cur * 256 + f], acc);
            acc = 0.f;
            cur = b;
        }
        float v = sc * (float)h[(size_t)r * 256 + f] + sh;
        acc += v > 0.f ? v : 0.f;
    }
    atomicAdd(&psum[cur * 256 + f], acc);
}

__global__ void pool_div(const float* __restrict__ psum, const int* __restrict__ cnt,
                         float* __restrict__ g) {
    int i = blockIdx.x * 256 + threadIdx.x;  // 64*256
    int b = i >> 8;
    float c = (float)max(cnt[b], 1);
    g[i] = psum[i] / c;
}

// ---- FC head: split-K with atomic accumulation (high TLP) ----
__global__ void fc_init(const float* __restrict__ b, float* __restrict__ Y, int rows, int N) {
    int i = blockIdx.x * blockDim.x + threadIdx.x;
    if (i < rows * N) Y[i] = b[i % N];
}

__global__ void fc_splitk(const float* __restrict__ X, const float* __restrict__ W,
                          float* __restrict__ Y, int K, int N, int KC) {
    int col = blockIdx.x * blockDim.x + threadIdx.x;
    int row = blockIdx.y;
    int k0 = blockIdx.z * KC;
    float acc = 0.f;
    const float* x = X + (size_t)row * K + k0;
    const float* w = W + (size_t)k0 * N + col;
#pragma unroll 8
    for (int k = 0; k < KC; ++k) acc += x[k] * w[(size_t)k * N];
    atomicAdd(&Y[(size_t)row * N + col], acc);
}

__global__ void relu_inplace(float* __restrict__ Y, int n) {
    int i = blockIdx.x * blockDim.x + threadIdx.x;
    if (i < n) Y[i] = Y[i] > 0.f ? Y[i] : 0.f;
}

// ---------------------------------------------------------------------------
extern "C" void kernel_launch(void* const* d_in, const int* in_sizes, int n_in,
                              void* d_out, int out_size, void* d_ws, size_t ws_size,
                              hipStream_t stream) {
    const float* x     = (const float*)d_in[0];
    const int*   ei    = (const int*)d_in[1];   // [2][E]: row0=src, row1=dst
    const int*   batch = (const int*)d_in[2];
    const float* Wg0 = (const float*)d_in[3],  *bg0 = (const float*)d_in[4];
    const float* gamma0 = (const float*)d_in[5], *beta0 = (const float*)d_in[6];
    const float* Wg1 = (const float*)d_in[7],  *bg1 = (const float*)d_in[8];
    const float* gamma1 = (const float*)d_in[9], *beta1 = (const float*)d_in[10];
    const float* Wg2 = (const float*)d_in[11], *bg2 = (const float*)d_in[12];
    const float* gamma2 = (const float*)d_in[13], *beta2 = (const float*)d_in[14];
    const float* Wf0 = (const float*)d_in[15], *bf0 = (const float*)d_in[16];
    const float* Wf1 = (const float*)d_in[17], *bf1 = (const float*)d_in[18];
    float* out = (float*)d_out;

    // ---- workspace carve (~120 MB; split-K partials alias f16 intermediates) ----
    size_t off = 0;
    auto alloc = [&](size_t bytes) {
        void* p = (char*)d_ws + off;
        off += (bytes + 255) & ~(size_t)255;
        return p;
    };
    f16*   hA16     = (f16*)alloc((size_t)N_NODES * 256 * 2);       // GEMM out / h16+agg16
    float* cp32     = (float*)alloc((size_t)2 * N_NODES * 128 * 4); // split-K partials (layer 0)
    f16*   hBn16    = (f16*)cp32;                                    // pre-BN buffer (aliases cp0/cp1)
    float* cp0      = cp32;
    float* cp1      = cp32 + (size_t)N_NODES * 128;
    f16*   h16      = hA16;                                          // post-BN layer0 (12.8 MB)
    f16*   agg16    = hA16 + (size_t)N_NODES * 128;                  // layer1 agg out (12.8 MB)
    int2*  csr      = (int2*)alloc((size_t)N_EDGES * 8);
    int*   deg      = (int*)alloc((size_t)N_NODES * 4);
    float* dinv     = (float*)alloc((size_t)N_NODES * 4);
    int*   rowstart = (int*)alloc((size_t)(N_NODES + 1) * 4);
    int*   pos      = (int*)alloc((size_t)N_NODES * 4);
    float* bnstat   = (float*)alloc(2 * 256 * 4);
    float* bnss     = (float*)alloc(2 * 256 * 4);
    float* psum     = (float*)alloc(64 * 256 * 4);
    int*   pcount   = (int*)alloc(64 * 4);
    float* gpool    = (float*)alloc(64 * 256 * 4);
    float* g1       = (float*)alloc(64 * 1024 * 4);
    f16*   W0t      = (f16*)alloc((size_t)1280 * 128 * 2);
    f16*   W1t      = (f16*)alloc((size_t)128 * 256 * 2);
    f16*   W2t      = (f16*)alloc((size_t)256 * 256 * 2);
    (void)ws_size;

    const int TPB = 256;
    const int nb_nodes = (N_NODES + TPB - 1) / TPB;
    const int nb_edges = (N_EDGES + TPB - 1) / TPB;

    // ---- graph structure + weight casts ----
    init_deg<<<nb_nodes, TPB, 0, stream>>>(deg);
    deg_count<<<nb_edges, TPB, 0, stream>>>(ei + N_EDGES, deg);
    make_dinv<<<nb_nodes, TPB, 0, stream>>>(deg, dinv);
    scan_deg<<<1, 1024, 0, stream>>>(deg, rowstart, pos);
    csr_fill<<<nb_edges, TPB, 0, stream>>>(ei, ei + N_EDGES, dinv, pos, csr);
    cast_w<<<(1280 * 128 + 255) / 256, 256, 0, stream>>>(Wg0, W0t, 1280, 128);
    cast_w<<<(128 * 256 + 255) / 256, 256, 0, stream>>>(Wg1, W1t, 128, 256);
    cast_w<<<(256 * 256 + 255) / 256, 256, 0, stream>>>(Wg2, W2t, 256, 256);

    const int tiles128 = (N_NODES + 127) / 128;                   // 391
    const int gemm0_blocks = tiles128 * 2;                        // 782
    const int gemmh_blocks = (1563 * 64 + TPB - 1) / TPB;         // 391
    const int agg_blocks = (N_NODES * 64 + TPB - 1) / TPB;        // 12500

    // ---- layer 0: 1280 -> 128 (LDS-staged barrier GEMM, split-K=2) ----
    gemm_x_lds<<<gemm0_blocks, TPB, 0, stream>>>(x, W0t, cp0, cp1, N_NODES);
    reduce_cast<<<(N_NODES * 128 / 4 + 255) / 256, 256, 0, stream>>>(cp0, cp1, hA16, N_NODES * 128 / 4);
    aggregate<128, true><<<agg_blocks, TPB, 0, stream>>>(hA16, rowstart, csr, dinv, bg0, hBn16);
    hipMemsetAsync(bnstat, 0, 2 * 128 * 4, stream);
    bn_stats<128><<<(N_NODES + 127) / 128, 128, 0, stream>>>(hBn16, bnstat);
    bn_finalize<128><<<1, 128, 0, stream>>>(bnstat, gamma0, beta0, bnss);

    // ---- layer 1: AGGREGATE-FIRST (linearity: agg(h)W = agg(hW)) ----
    // h16 = relu(bn(hBn16))  [post-BN layer0, 128d]
    bn_apply_relu<128><<<(N_NODES * 128 / 8 + 255) / 256, 256, 0, stream>>>(hBn16, bnss, h16);
    // agg16 = aggregate(h16) in 128d (half the gather traffic of 256d), NO bias
    aggregate<128, false><<<agg_blocks, TPB, 0, stream>>>(h16, rowstart, csr, dinv, nullptr, agg16);
    // hBn16 = agg16 @ W1 + b1  [pre-BN layer1, 256d]
    gemm_h_bias_pipe<128><<<dim3(gemmh_blocks, 2), TPB, 0, stream>>>(agg16, W1t, bg1, hBn16, 256);
    hipMemsetAsync(bnstat, 0, 2 * 256 * 4, stream);
    bn_stats<256><<<(N_NODES + 127) / 128, 256, 0, stream>>>(hBn16, bnstat);
    bn_finalize<256><<<1, 256, 0, stream>>>(bnstat, gamma1, beta1, bnss);

    // ---- layer 2: transform-first (256->256, no traffic advantage either way) ----
    gemm_h_bn_pipe<256><<<dim3(gemmh_blocks, 2), TPB, 0, stream>>>(hBn16, bnss, W2t, hA16, 256);
    aggregate<256, true><<<agg_blocks, TPB, 0, stream>>>(hA16, rowstart, csr, dinv, bg2, hBn16);
    hipMemsetAsync(bnstat, 0, 2 * 256 * 4, stream);
    bn_stats<256><<<(N_NODES + 127) / 128, 256, 0, stream>>>(hBn16, bnstat);
    bn_finalize<256><<<1, 256, 0, stream>>>(bnstat, gamma2, beta2, bnss);

    // ---- global mean pool (BN+ReLU fused) ----
    hipMemsetAsync(psum, 0, 64 * 256 * 4, stream);
    count_batch_bs<<<1, 64, 0, stream>>>(batch, pcount);
    pool_seg_bn<<<(N_NODES + 63) / 64, 256, 0, stream>>>(hBn16, bnss, batch, psum);
    pool_div<<<64, 256, 0, stream>>>(psum, pcount, gpool);

    // ---- FC head (split-K, atomic accumulate) ----
    fc_init<<<(64 * 1024 + 255) / 256, 256, 0, stream>>>(bf0, g1, 64, 1024);
    fc_splitk<<<dim3(4, 64, 4), 256, 0, stream>>>(gpool, Wf0, g1, 256, 1024, 64);
    relu_inplace<<<(64 * 1024 + 255) / 256, 256, 0, stream>>>(g1, 64 * 1024);
    fc_init<<<(64 * 128 + 255) / 256, 256, 0, stream>>>(bf1, out, 64, 128);
    fc_splitk<<<dim3(1, 64, 16), 128, 0, stream>>>(g1, Wf1, out, 1024, 128, 64);
}

// Round 17
// 804.328 us; speedup vs baseline: 1.9823x; 1.0086x over previous
//
#include <hip/hip_runtime.h>
#include <hip/hip_bf16.h>

#define N_NODES 50000
#define N_EDGES 1600000
#define N_GRAPHS 64

typedef _Float16 f16;
typedef _Float16 f16x8 __attribute__((ext_vector_type(8)));
typedef _Float16 f16x4 __attribute__((ext_vector_type(4)));
typedef _Float16 f16x2 __attribute__((ext_vector_type(2)));
typedef float f32x4 __attribute__((ext_vector_type(4)));

template <int V> struct VecT;
template <> struct VecT<2> { using type = f16x2; };
template <> struct VecT<4> { using type = f16x4; };

// async global->LDS (16B per lane; LDS dest = wave-uniform base + lane*16)
typedef __attribute__((address_space(3))) void lds_void_t;
typedef const __attribute__((address_space(1))) void gbl_void_t;
__device__ __forceinline__ void gload_lds16(const void* g, void* l) {
    __builtin_amdgcn_global_load_lds((gbl_void_t*)g, (lds_void_t*)l, 16, 0, 0);
}

// ---------------------------------------------------------------------------
// Graph-structure construction
// ---------------------------------------------------------------------------
__global__ void init_deg(int* deg) {
    int i = blockIdx.x * blockDim.x + threadIdx.x;
    if (i < N_NODES) deg[i] = 1;  // self-loop
}

__global__ void deg_count(const int* __restrict__ dst, int* __restrict__ deg) {
    int e = blockIdx.x * blockDim.x + threadIdx.x;
    if (e < N_EDGES) atomicAdd(&deg[dst[e]], 1);
}

__global__ void make_dinv(const int* __restrict__ deg, float* __restrict__ dinv) {
    int i = blockIdx.x * blockDim.x + threadIdx.x;
    if (i < N_NODES) dinv[i] = rsqrtf((float)deg[i]);
}

// single-block scan over edge-only degrees -> rowstart[N+1], pos[N]
__global__ void scan_deg(const int* __restrict__ deg, int* __restrict__ rowstart,
                         int* __restrict__ pos) {
    __shared__ int wsum[16];
    __shared__ int carry_s;
    const int t = threadIdx.x;
    const int lane = t & 63;
    const int w = t >> 6;
    if (t == 0) carry_s = 0;
    __syncthreads();
    for (int base = 0; base < N_NODES; base += 1024) {
        int i = base + t;
        int v = (i < N_NODES) ? (deg[i] - 1) : 0;  // exclude self loop
        int s = v;
#pragma unroll
        for (int off = 1; off < 64; off <<= 1) {
            int n = __shfl_up(s, off, 64);
            if (lane >= off) s += n;
        }
        if (lane == 63) wsum[w] = s;
        __syncthreads();
        if (w == 0) {
            int ws = (lane < 16) ? wsum[lane] : 0;
#pragma unroll
            for (int off = 1; off < 16; off <<= 1) {
                int n = __shfl_up(ws, off, 64);
                if (lane >= off) ws += n;
            }
            if (lane < 16) wsum[lane] = ws;
        }
        __syncthreads();
        int waveoff = (w == 0) ? 0 : wsum[w - 1];
        int carry = carry_s;
        int excl = carry + waveoff + s - v;
        if (i < N_NODES) {
            rowstart[i] = excl;
            pos[i] = excl;
        }
        __syncthreads();
        if (t == 0) carry_s = carry + wsum[15];
        __syncthreads();
    }
    if (t == 0) rowstart[N_NODES] = carry_s;
}

// packed CSR entry: .x = src node, .y = norm (float bits)
__global__ void csr_fill(const int* __restrict__ src, const int* __restrict__ dst,
                         const float* __restrict__ dinv, int* __restrict__ pos,
                         int2* __restrict__ csr) {
    int e = blockIdx.x * blockDim.x + threadIdx.x;
    if (e >= N_EDGES) return;
    int s = src[e], d = dst[e];
    int slot = atomicAdd(&pos[d], 1);
    csr[slot] = make_int2(s, __float_as_int(dinv[s] * dinv[d]));
}

// ---------------------------------------------------------------------------
// Weight cast+transpose: Wt[n][k] = (f16) W[k][n]
// ---------------------------------------------------------------------------
__global__ void cast_w(const float* __restrict__ W, f16* __restrict__ Wt, int K, int N) {
    int i = blockIdx.x * blockDim.x + threadIdx.x;
    if (i >= K * N) return;
    int k = i % K, n = i / K;
    Wt[i] = (f16)W[(size_t)k * N + n];
}

// ---------------------------------------------------------------------------
// MFMA GEMM layer 0, LDS-staged, BK=64: block = 4 waves, tile 128 rows x 128
// cols, split-K=2 (blockIdx.x = tile*2 + s).  Per step each wave stages its
// 32 rows x 64 k-cols (256 B contiguous per row -> full-efficiency HBM
// bursts) via 8 async global_load_lds, then computes 2 MFMA sub-tiles.
// Barrier count halved vs BK=32.  Chunk-swizzle: 16x 16B chunks per row,
// stored slot s holds global chunk s^(row&15) (source pre-swizzled, read
// applies same XOR; LDS dest linear per rule #21).  ds_read 2-way bank alias
// only (free per m136).
// ---------------------------------------------------------------------------
__launch_bounds__(256)
__global__ void gemm_x_lds(const float* __restrict__ A, const f16* __restrict__ Bt,
                           float* __restrict__ C0, float* __restrict__ C1, int M) {
    const int K = 1280;
    __shared__ float Asm[128 * 64];  // 32 KB
    const int t = threadIdx.x;
    const int w = t >> 6, lane = t & 63;
    const int tile = blockIdx.x >> 1, s = blockIdx.x & 1;
    const int m0 = tile * 128;
    const int kbeg = s * 640;
    float* __restrict__ C = s ? C1 : C0;
    const int r = lane & 15, q = lane >> 4;

    // staging: call i covers this wave's rows i*4 + (lane>>4); lane slot = lane&15
    const int rl_sub = lane >> 4;              // 0..3 (row within 4-row group)
    // compute-side row bases
    const float* base0 = Asm + (w * 32 + r) * 64;
    const float* base1 = Asm + (w * 32 + 16 + r) * 64;

    const f16* bp = Bt + (size_t)r * K + kbeg + q * 8;

    f32x4 acc[2][8];
#pragma unroll
    for (int i = 0; i < 2; ++i)
#pragma unroll
        for (int j = 0; j < 8; ++j) acc[i][j] = (f32x4){0.f, 0.f, 0.f, 0.f};

    for (int kt = 0; kt < 10; ++kt) {
        const int kk = kbeg + kt * 64;
        // ---- async stage A tile: 8 calls/wave, 1 KB each (4 rows x 256 B) ----
#pragma unroll
        for (int i = 0; i < 8; ++i) {
            const int row_l = i * 4 + rl_sub;              // 0..31 within wave
            int row_g = m0 + w * 32 + row_l;
            row_g = row_g < M ? row_g : M - 1;
            const int gch = (lane & 15) ^ (row_l & 15);    // pre-swizzled source chunk
            const float* src = A + (size_t)row_g * K + kk + gch * 4;
            float* dst = Asm + (w * 32 + i * 4) * 64;      // wave-uniform base
            gload_lds16(src, dst);
        }
        __syncthreads();  // drains vmcnt before barrier
        // ---- 2 MFMA sub-tiles from LDS ----
#pragma unroll
        for (int kt2 = 0; kt2 < 2; ++kt2) {
            float4 u0 = *(const float4*)(base0 + (((kt2 * 8 + 2 * q) ^ r) << 2));
            float4 v0 = *(const float4*)(base0 + (((kt2 * 8 + 2 * q + 1) ^ r) << 2));
            float4 u1 = *(const float4*)(base1 + (((kt2 * 8 + 2 * q) ^ r) << 2));
            float4 v1 = *(const float4*)(base1 + (((kt2 * 8 + 2 * q + 1) ^ r) << 2));
            f16x8 af0 = {(f16)u0.x, (f16)u0.y, (f16)u0.z, (f16)u0.w,
                         (f16)v0.x, (f16)v0.y, (f16)v0.z, (f16)v0.w};
            f16x8 af1 = {(f16)u1.x, (f16)u1.y, (f16)u1.z, (f16)u1.w,
                         (f16)v1.x, (f16)v1.y, (f16)v1.z, (f16)v1.w};
#pragma unroll
            for (int ni = 0; ni < 8; ++ni) {
                f16x8 bf = *(const f16x8*)(bp + (size_t)ni * 16 * K + kt * 64 + kt2 * 32);
                acc[0][ni] = __builtin_amdgcn_mfma_f32_16x16x32_f16(af0, bf, acc[0][ni], 0, 0, 0);
                acc[1][ni] = __builtin_amdgcn_mfma_f32_16x16x32_f16(af1, bf, acc[1][ni], 0, 0, 0);
            }
        }
        __syncthreads();  // protect LDS before next stage
    }
#pragma unroll
    for (int mi = 0; mi < 2; ++mi)
#pragma unroll
        for (int j = 0; j < 4; ++j) {
            int row = m0 + w * 32 + mi * 16 + q * 4 + j;
            if (row < M) {
                float* cp = C + (size_t)row * 128 + r;
#pragma unroll
                for (int ni = 0; ni < 8; ++ni) cp[ni * 16] = acc[mi][ni][j];
            }
        }
}

// sum split-K partials, cast to f16 (vectorized x4)
__global__ void reduce_cast(const float* __restrict__ c0, const float* __restrict__ c1,
                            f16* __restrict__ o, int n4) {
    int i = blockIdx.x * blockDim.x + threadIdx.x;
    if (i >= n4) return;
    float4 a = ((const float4*)c0)[i];
    float4 b = ((const float4*)c1)[i];
    f16x4 r = {(f16)(a.x + b.x), (f16)(a.y + b.y), (f16)(a.z + b.z), (f16)(a.w + b.w)};
    ((f16x4*)o)[i] = r;
}

// ---------------------------------------------------------------------------
// MFMA GEMM, fused BN+ReLU on A (layer 2), 32 rows/wave, 2-stage pipeline.
// ---------------------------------------------------------------------------
template <int K>
__launch_bounds__(256)
__global__ void gemm_h_bn_pipe(const f16* __restrict__ A16, const float* __restrict__ ss,
                               const f16* __restrict__ Bt, f16* __restrict__ C16, int N) {
    constexpr int NT = K / 32;
    const int gw = (int)((blockIdx.x * blockDim.x + threadIdx.x) >> 6);
    const int lane = threadIdx.x & 63;
    const int m0 = gw * 32;
    if (m0 >= N_NODES) return;
    const int col0 = blockIdx.y * 128;
    const int r = lane & 15, q = lane >> 4;
    int row0 = m0 + r;       row0 = row0 < N_NODES ? row0 : N_NODES - 1;
    int row1 = m0 + 16 + r;  row1 = row1 < N_NODES ? row1 : N_NODES - 1;
    const f16* a0 = A16 + (size_t)row0 * K + q * 8;
    const f16* a1 = A16 + (size_t)row1 * K + q * 8;
    const f16* bp = Bt + (size_t)(col0 + r) * K + q * 8;
    const float* scp = ss + q * 8;
    const float* shp = ss + K + q * 8;

    f32x4 acc[2][8];
#pragma unroll
    for (int i = 0; i < 2; ++i)
#pragma unroll
        for (int j = 0; j < 8; ++j) acc[i][j] = (f32x4){0.f, 0.f, 0.f, 0.f};

    f16x8 ab[2][2];
    f16x8 bb[2][8];
    float4 sb[2][4];
    ab[0][0] = *(const f16x8*)(a0);
    ab[0][1] = *(const f16x8*)(a1);
    sb[0][0] = *(const float4*)(scp);
    sb[0][1] = *(const float4*)(scp + 4);
    sb[0][2] = *(const float4*)(shp);
    sb[0][3] = *(const float4*)(shp + 4);
#pragma unroll
    for (int ni = 0; ni < 8; ++ni) bb[0][ni] = *(const f16x8*)(bp + (size_t)ni * 16 * K);

#pragma unroll
    for (int kt = 0; kt < NT; ++kt) {
        const int cur = kt & 1, nxt = cur ^ 1;
        if (kt < NT - 1) {
            const int ko = (kt + 1) * 32;
            ab[nxt][0] = *(const f16x8*)(a0 + ko);
            ab[nxt][1] = *(const f16x8*)(a1 + ko);
            sb[nxt][0] = *(const float4*)(scp + ko);
            sb[nxt][1] = *(const float4*)(scp + ko + 4);
            sb[nxt][2] = *(const float4*)(shp + ko);
            sb[nxt][3] = *(const float4*)(shp + ko + 4);
#pragma unroll
            for (int ni = 0; ni < 8; ++ni)
                bb[nxt][ni] = *(const f16x8*)(bp + (size_t)ni * 16 * K + ko);
        }
        float sc[8] = {sb[cur][0].x, sb[cur][0].y, sb[cur][0].z, sb[cur][0].w,
                       sb[cur][1].x, sb[cur][1].y, sb[cur][1].z, sb[cur][1].w};
        float sh[8] = {sb[cur][2].x, sb[cur][2].y, sb[cur][2].z, sb[cur][2].w,
                       sb[cur][3].x, sb[cur][3].y, sb[cur][3].z, sb[cur][3].w};
        f16x8 af0, af1;
#pragma unroll
        for (int j = 0; j < 8; ++j) {
            float v0 = (float)ab[cur][0][j] * sc[j] + sh[j];
            float v1 = (float)ab[cur][1][j] * sc[j] + sh[j];
            af0[j] = (f16)(v0 > 0.f ? v0 : 0.f);
            af1[j] = (f16)(v1 > 0.f ? v1 : 0.f);
        }
#pragma unroll
        for (int ni = 0; ni < 8; ++ni) {
            acc[0][ni] = __builtin_amdgcn_mfma_f32_16x16x32_f16(af0, bb[cur][ni], acc[0][ni], 0, 0, 0);
            acc[1][ni] = __builtin_amdgcn_mfma_f32_16x16x32_f16(af1, bb[cur][ni], acc[1][ni], 0, 0, 0);
        }
    }
#pragma unroll
    for (int mi = 0; mi < 2; ++mi)
#pragma unroll
        for (int j = 0; j < 4; ++j) {
            int row = m0 + mi * 16 + q * 4 + j;
            if (row < N_NODES) {
                f16* cp = C16 + (size_t)row * N + col0 + r;
#pragma unroll
                for (int ni = 0; ni < 8; ++ni) cp[ni * 16] = (f16)acc[mi][ni][j];
            }
        }
}

// ---------------------------------------------------------------------------
// MFMA GEMM, plain A + bias in epilogue (layer 1, aggregate-first order):
// ---------------------------------------------------------------------------
template <int K>
__launch_bounds__(256)
__global__ void gemm_h_bias_pipe(const f16* __restrict__ A16, const f16* __restrict__ Bt,
                                 const float* __restrict__ bias, f16* __restrict__ C16, int N) {
    constexpr int NT = K / 32;
    const int gw = (int)((blockIdx.x * blockDim.x + threadIdx.x) >> 6);
    const int lane = threadIdx.x & 63;
    const int m0 = gw * 32;
    if (m0 >= N_NODES) return;
    const int col0 = blockIdx.y * 128;
    const int r = lane & 15, q = lane >> 4;
    int row0 = m0 + r;       row0 = row0 < N_NODES ? row0 : N_NODES - 1;
    int row1 = m0 + 16 + r;  row1 = row1 < N_NODES ? row1 : N_NODES - 1;
    const f16* a0 = A16 + (size_t)row0 * K + q * 8;
    const f16* a1 = A16 + (size_t)row1 * K + q * 8;
    const f16* bp = Bt + (size_t)(col0 + r) * K + q * 8;

    f32x4 acc[2][8];
#pragma unroll
    for (int i = 0; i < 2; ++i)
#pragma unroll
        for (int j = 0; j < 8; ++j) acc[i][j] = (f32x4){0.f, 0.f, 0.f, 0.f};

    f16x8 ab[2][2];
    f16x8 bb[2][8];
    ab[0][0] = *(const f16x8*)(a0);
    ab[0][1] = *(const f16x8*)(a1);
#pragma unroll
    for (int ni = 0; ni < 8; ++ni) bb[0][ni] = *(const f16x8*)(bp + (size_t)ni * 16 * K);

#pragma unroll
    for (int kt = 0; kt < NT; ++kt) {
        const int cur = kt & 1, nxt = cur ^ 1;
        if (kt < NT - 1) {
            const int ko = (kt + 1) * 32;
            ab[nxt][0] = *(const f16x8*)(a0 + ko);
            ab[nxt][1] = *(const f16x8*)(a1 + ko);
#pragma unroll
            for (int ni = 0; ni < 8; ++ni)
                bb[nxt][ni] = *(const f16x8*)(bp + (size_t)ni * 16 * K + ko);
        }
#pragma unroll
        for (int ni = 0; ni < 8; ++ni) {
            acc[0][ni] = __builtin_amdgcn_mfma_f32_16x16x32_f16(ab[cur][0], bb[cur][ni], acc[0][ni], 0, 0, 0);
            acc[1][ni] = __builtin_amdgcn_mfma_f32_16x16x32_f16(ab[cur][1], bb[cur][ni], acc[1][ni], 0, 0, 0);
        }
    }
    float bv[8];
#pragma unroll
    for (int ni = 0; ni < 8; ++ni) bv[ni] = bias[col0 + ni * 16 + r];
#pragma unroll
    for (int mi = 0; mi < 2; ++mi)
#pragma unroll
        for (int j = 0; j < 4; ++j) {
            int row = m0 + mi * 16 + q * 4 + j;
            if (row < N_NODES) {
                f16* cp = C16 + (size_t)row * N + col0 + r;
#pragma unroll
                for (int ni = 0; ni < 8; ++ni) cp[ni * 16] = (f16)(acc[mi][ni][j] + bv[ni]);
            }
        }
}

// ---------------------------------------------------------------------------
// Edge aggregation (f16 gather, fp32 accumulate, f16 out): one wave per node.
// 8-deep unrolled gather loop.  BIAS toggles the +bias epilogue.
// ---------------------------------------------------------------------------
template <int D, bool BIAS>
__launch_bounds__(256)
__global__ void aggregate(const f16* __restrict__ h, const int* __restrict__ rowstart,
                          const int2* __restrict__ csr, const float* __restrict__ dinv,
                          const float* __restrict__ bias, f16* __restrict__ out) {
    constexpr int V = D / 64;  // f16 per lane (2 or 4)
    using vec = typename VecT<V>::type;
    int w = (int)((blockIdx.x * blockDim.x + threadIdx.x) >> 6);
    int lane = threadIdx.x & 63;
    if (w >= N_NODES) return;
    float acc[V];
    float di = dinv[w];
    vec self = *(const vec*)(h + (size_t)w * D + lane * V);
#pragma unroll
    for (int v = 0; v < V; ++v) acc[v] = (float)self[v] * (di * di);
    int e0 = rowstart[w], e1 = rowstart[w + 1];
    int j = e0;
    for (; j + 8 <= e1; j += 8) {
        int2 c[8];
        vec rr[8];
#pragma unroll
        for (int u = 0; u < 8; ++u) c[u] = csr[j + u];
#pragma unroll
        for (int u = 0; u < 8; ++u)
            rr[u] = *(const vec*)(h + (size_t)c[u].x * D + lane * V);
#pragma unroll
        for (int u = 0; u < 8; ++u) {
            float nm = __int_as_float(c[u].y);
#pragma unroll
            for (int v = 0; v < V; ++v) acc[v] += (float)rr[u][v] * nm;
        }
    }
    if (j + 4 <= e1) {
        int2 c0 = csr[j], c1 = csr[j + 1], c2 = csr[j + 2], c3 = csr[j + 3];
        vec r0 = *(const vec*)(h + (size_t)c0.x * D + lane * V);
        vec r1 = *(const vec*)(h + (size_t)c1.x * D + lane * V);
        vec r2 = *(const vec*)(h + (size_t)c2.x * D + lane * V);
        vec r3 = *(const vec*)(h + (size_t)c3.x * D + lane * V);
        float n0 = __int_as_float(c0.y), n1 = __int_as_float(c1.y);
        float n2 = __int_as_float(c2.y), n3 = __int_as_float(c3.y);
#pragma unroll
        for (int v = 0; v < V; ++v)
            acc[v] += (float)r0[v] * n0 + (float)r1[v] * n1 +
                      (float)r2[v] * n2 + (float)r3[v] * n3;
        j += 4;
    }
    for (; j < e1; ++j) {
        int2 c = csr[j];
        vec r = *(const vec*)(h + (size_t)c.x * D + lane * V);
        float nm = __int_as_float(c.y);
#pragma unroll
        for (int v = 0; v < V; ++v) acc[v] += (float)r[v] * nm;
    }
    vec o;
#pragma unroll
    for (int v = 0; v < V; ++v)
        o[v] = (f16)(BIAS ? (acc[v] + bias[lane * V + v]) : acc[v]);
    *(vec*)(out + (size_t)w * D + lane * V) = o;
}

// ---------------------------------------------------------------------------
// BatchNorm stats (training, biased var) over pre-BN activations
// ---------------------------------------------------------------------------
template <int D>
__global__ void bn_stats(const f16* __restrict__ h, float* __restrict__ stat) {
    int f = threadIdx.x;  // D threads
    int r0 = blockIdx.x * 128;
    int r1 = min(r0 + 128, N_NODES);
    float s = 0.f, s2 = 0.f;
    for (int r = r0; r < r1; ++r) {
        float v = (float)h[(size_t)r * D + f];
        s += v;
        s2 += v * v;
    }
    atomicAdd(&stat[f], s);
    atomicAdd(&stat[D + f], s2);
}

template <int D>
__global__ void bn_finalize(const float* __restrict__ stat, const float* __restrict__ gamma,
                            const float* __restrict__ beta, float* __restrict__ ss) {
    int f = threadIdx.x;
    float m = stat[f] * (1.0f / N_NODES);
    float var = stat[D + f] * (1.0f / N_NODES) - m * m;
    float sc = gamma[f] * rsqrtf(var + 1e-5f);
    ss[f] = sc;
    ss[D + f] = beta[f] - m * sc;
}

// BN+ReLU apply pass: hout = relu(sc*hin + sh), f16 in/out, vectorized x8
template <int D>
__global__ void bn_apply_relu(const f16* __restrict__ hin, const float* __restrict__ ss,
                              f16* __restrict__ hout) {
    int i = blockIdx.x * blockDim.x + threadIdx.x;  // 8 f16 per thread
    if (i >= N_NODES * D / 8) return;
    int f0 = (i * 8) & (D - 1);
    f16x8 v = ((const f16x8*)hin)[i];
    f16x8 r;
#pragma unroll
    for (int j = 0; j < 8; ++j) {
        float val = (float)v[j] * ss[f0 + j] + ss[D + f0 + j];
        r[j] = (f16)(val > 0.f ? val : 0.f);
    }
    ((f16x8*)hout)[i] = r;
}

// ---------------------------------------------------------------------------
// Pool (batch sorted) with fused BN+ReLU, + FC head
// ---------------------------------------------------------------------------
__global__ void count_batch_bs(const int* __restrict__ batch, int* __restrict__ cnt) {
    int g = threadIdx.x;  // one block, 64 threads
    if (g >= N_GRAPHS) return;
    int lo = 0, hi = N_NODES;
    while (lo < hi) { int mid = (lo + hi) >> 1; if (batch[mid] < g) lo = mid + 1; else hi = mid; }
    int b0 = lo;
    lo = 0; hi = N_NODES;
    while (lo < hi) { int mid = (lo + hi) >> 1; if (batch[mid] < g + 1) lo = mid + 1; else hi = mid; }
    cnt[g] = lo - b0;
}

__global__ void pool_seg_bn(const f16* __restrict__ h, const float* __restrict__ ss,
                            const int* __restrict__ batch, float* __restrict__ psum) {
    int f = threadIdx.x;  // 256
    float sc = ss[f], sh = ss[256 + f];
    int r0 = blockIdx.x * 64;
    int r1 = min(r0 + 64, N_NODES);
    float acc = 0.f;
    int cur = batch[r0];
    for (int r = r0; r < r1; ++r) {
        int b = batch[r];
        if (b != cur) {
            atomicAdd(&psum[cur * 256 + f], acc);
            acc = 0.f;
            cur = b;
        }
        float v = sc * (float)h[(size_t)r * 256 + f] + sh;
        acc += v > 0.f ? v : 0.f;
    }
    atomicAdd(&psum[cur * 256 + f], acc);
}

__global__ void pool_div(const float* __restrict__ psum, const int* __restrict__ cnt,
                         float* __restrict__ g) {
    int i = blockIdx.x * 256 + threadIdx.x;  // 64*256
    int b = i >> 8;
    float c = (float)max(cnt[b], 1);
    g[i] = psum[i] / c;
}

// ---- FC head: split-K with atomic accumulation (high TLP) ----
__global__ void fc_init(const float* __restrict__ b, float* __restrict__ Y, int rows, int N) {
    int i = blockIdx.x * blockDim.x + threadIdx.x;
    if (i < rows * N) Y[i] = b[i % N];
}

__global__ void fc_splitk(const float* __restrict__ X, const float* __restrict__ W,
                          float* __restrict__ Y, int K, int N, int KC) {
    int col = blockIdx.x * blockDim.x + threadIdx.x;
    int row = blockIdx.y;
    int k0 = blockIdx.z * KC;
    float acc = 0.f;
    const float* x = X + (size_t)row * K + k0;
    const float* w = W + (size_t)k0 * N + col;
#pragma unroll 8
    for (int k = 0; k < KC; ++k) acc += x[k] * w[(size_t)k * N];
    atomicAdd(&Y[(size_t)row * N + col], acc);
}

__global__ void relu_inplace(float* __restrict__ Y, int n) {
    int i = blockIdx.x * blockDim.x + threadIdx.x;
    if (i < n) Y[i] = Y[i] > 0.f ? Y[i] : 0.f;
}

// ---------------------------------------------------------------------------
extern "C" void kernel_launch(void* const* d_in, const int* in_sizes, int n_in,
                              void* d_out, int out_size, void* d_ws, size_t ws_size,
                              hipStream_t stream) {
    const float* x     = (const float*)d_in[0];
    const int*   ei    = (const int*)d_in[1];   // [2][E]: row0=src, row1=dst
    const int*   batch = (const int*)d_in[2];
    const float* Wg0 = (const float*)d_in[3],  *bg0 = (const float*)d_in[4];
    const float* gamma0 = (const float*)d_in[5], *beta0 = (const float*)d_in[6];
    const float* Wg1 = (const float*)d_in[7],  *bg1 = (const float*)d_in[8];
    const float* gamma1 = (const float*)d_in[9], *beta1 = (const float*)d_in[10];
    const float* Wg2 = (const float*)d_in[11], *bg2 = (const float*)d_in[12];
    const float* gamma2 = (const float*)d_in[13], *beta2 = (const float*)d_in[14];
    const float* Wf0 = (const float*)d_in[15], *bf0 = (const float*)d_in[16];
    const float* Wf1 = (const float*)d_in[17], *bf1 = (const float*)d_in[18];
    float* out = (float*)d_out;

    // ---- workspace carve (~120 MB; split-K partials alias f16 intermediates) ----
    size_t off = 0;
    auto alloc = [&](size_t bytes) {
        void* p = (char*)d_ws + off;
        off += (bytes + 255) & ~(size_t)255;
        return p;
    };
    f16*   hA16     = (f16*)alloc((size_t)N_NODES * 256 * 2);       // GEMM out / h16+agg16
    float* cp32     = (float*)alloc((size_t)2 * N_NODES * 128 * 4); // split-K partials (layer 0)
    f16*   hBn16    = (f16*)cp32;                                    // pre-BN buffer (aliases cp0/cp1)
    float* cp0      = cp32;
    float* cp1      = cp32 + (size_t)N_NODES * 128;
    f16*   h16      = hA16;                                          // post-BN layer0 (12.8 MB)
    f16*   agg16    = hA16 + (size_t)N_NODES * 128;                  // layer1 agg out (12.8 MB)
    int2*  csr      = (int2*)alloc((size_t)N_EDGES * 8);
    int*   deg      = (int*)alloc((size_t)N_NODES * 4);
    float* dinv     = (float*)alloc((size_t)N_NODES * 4);
    int*   rowstart = (int*)alloc((size_t)(N_NODES + 1) * 4);
    int*   pos      = (int*)alloc((size_t)N_NODES * 4);
    float* bnstat   = (float*)alloc(2 * 256 * 4);
    float* bnss     = (float*)alloc(2 * 256 * 4);
    float* psum     = (float*)alloc(64 * 256 * 4);
    int*   pcount   = (int*)alloc(64 * 4);
    float* gpool    = (float*)alloc(64 * 256 * 4);
    float* g1       = (float*)alloc(64 * 1024 * 4);
    f16*   W0t      = (f16*)alloc((size_t)1280 * 128 * 2);
    f16*   W1t      = (f16*)alloc((size_t)128 * 256 * 2);
    f16*   W2t      = (f16*)alloc((size_t)256 * 256 * 2);
    (void)ws_size;

    const int TPB = 256;
    const int nb_nodes = (N_NODES + TPB - 1) / TPB;
    const int nb_edges = (N_EDGES + TPB - 1) / TPB;

    // ---- graph structure + weight casts ----
    init_deg<<<nb_nodes, TPB, 0, stream>>>(deg);
    deg_count<<<nb_edges, TPB, 0, stream>>>(ei + N_EDGES, deg);
    make_dinv<<<nb_nodes, TPB, 0, stream>>>(deg, dinv);
    scan_deg<<<1, 1024, 0, stream>>>(deg, rowstart, pos);
    csr_fill<<<nb_edges, TPB, 0, stream>>>(ei, ei + N_EDGES, dinv, pos, csr);
    cast_w<<<(1280 * 128 + 255) / 256, 256, 0, stream>>>(Wg0, W0t, 1280, 128);
    cast_w<<<(128 * 256 + 255) / 256, 256, 0, stream>>>(Wg1, W1t, 128, 256);
    cast_w<<<(256 * 256 + 255) / 256, 256, 0, stream>>>(Wg2, W2t, 256, 256);

    const int tiles128 = (N_NODES + 127) / 128;                   // 391
    const int gemm0_blocks = tiles128 * 2;                        // 782
    const int gemmh_blocks = (1563 * 64 + TPB - 1) / TPB;         // 391
    const int agg_blocks = (N_NODES * 64 + TPB - 1) / TPB;        // 12500

    // ---- layer 0: 1280 -> 128 (LDS-staged BK=64 GEMM, split-K=2) ----
    gemm_x_lds<<<gemm0_blocks, TPB, 0, stream>>>(x, W0t, cp0, cp1, N_NODES);
    reduce_cast<<<(N_NODES * 128 / 4 + 255) / 256, 256, 0, stream>>>(cp0, cp1, hA16, N_NODES * 128 / 4);
    aggregate<128, true><<<agg_blocks, TPB, 0, stream>>>(hA16, rowstart, csr, dinv, bg0, hBn16);
    hipMemsetAsync(bnstat, 0, 2 * 128 * 4, stream);
    bn_stats<128><<<(N_NODES + 127) / 128, 128, 0, stream>>>(hBn16, bnstat);
    bn_finalize<128><<<1, 128, 0, stream>>>(bnstat, gamma0, beta0, bnss);

    // ---- layer 1: AGGREGATE-FIRST (linearity: agg(h)W = agg(hW)) ----
    bn_apply_relu<128><<<(N_NODES * 128 / 8 + 255) / 256, 256, 0, stream>>>(hBn16, bnss, h16);
    aggregate<128, false><<<agg_blocks, TPB, 0, stream>>>(h16, rowstart, csr, dinv, nullptr, agg16);
    gemm_h_bias_pipe<128><<<dim3(gemmh_blocks, 2), TPB, 0, stream>>>(agg16, W1t, bg1, hBn16, 256);
    hipMemsetAsync(bnstat, 0, 2 * 256 * 4, stream);
    bn_stats<256><<<(N_NODES + 127) / 128, 256, 0, stream>>>(hBn16, bnstat);
    bn_finalize<256><<<1, 256, 0, stream>>>(bnstat, gamma1, beta1, bnss);

    // ---- layer 2: transform-first (256->256) ----
    gemm_h_bn_pipe<256><<<dim3(gemmh_blocks, 2), TPB, 0, stream>>>(hBn16, bnss, W2t, hA16, 256);
    aggregate<256, true><<<agg_blocks, TPB, 0, stream>>>(hA16, rowstart, csr, dinv, bg2, hBn16);
    hipMemsetAsync(bnstat, 0, 2 * 256 * 4, stream);
    bn_stats<256><<<(N_NODES + 127) / 128, 256, 0, stream>>>(hBn16, bnstat);
    bn_finalize<256><<<1, 256, 0, stream>>>(bnstat, gamma2, beta2, bnss);

    // ---- global mean pool (BN+ReLU fused) ----
    hipMemsetAsync(psum, 0, 64 * 256 * 4, stream);
    count_batch_bs<<<1, 64, 0, stream>>>(batch, pcount);
    pool_seg_bn<<<(N_NODES + 63) / 64, 256, 0, stream>>>(hBn16, bnss, batch, psum);
    pool_div<<<64, 256, 0, stream>>>(psum, pcount, gpool);

    // ---- FC head (split-K, atomic accumulate) ----
    fc_init<<<(64 * 1024 + 255) / 256, 256, 0, stream>>>(bf0, g1, 64, 1024);
    fc_splitk<<<dim3(4, 64, 4), 256, 0, stream>>>(gpool, Wf0, g1, 256, 1024, 64);
    relu_inplace<<<(64 * 1024 + 255) / 256, 256, 0, stream>>>(g1, 64 * 1024);
    fc_init<<<(64 * 128 + 255) / 256, 256, 0, stream>>>(bf1, out, 64, 128);
    fc_splitk<<<dim3(1, 64, 16), 128, 0, stream>>>(g1, Wf1, out, 1024, 128, 64);
}